// Round 8
// baseline (196.834 us; speedup 1.0000x reference)
//
#include <hip/hip_runtime.h>

// ---------- types / helpers ----------
typedef __bf16 bf16x8 __attribute__((ext_vector_type(8)));
typedef float f32x4 __attribute__((ext_vector_type(4)));

struct alignas(16) US8 { unsigned short us[8]; };

static __device__ inline unsigned short f2bf(float f) {
  union { float f; unsigned u; } v; v.f = f;
  unsigned r = v.u + 0x7fffu + ((v.u >> 16) & 1u);   // RNE
  return (unsigned short)(r >> 16);
}

// B=8, N=4096, D=128.  32768 total rows.
#define NSEQ 4096
#define DIM 128
#define ROWS 32768
#define KH 2                      // cross-block key splits in attn

// log2(e)/sqrt(128): folded into q so S exits QK^T already in log2 domain
#define EXPC (1.4426950408889634f * 0.08838834764831845f)

// ---------- prep: weight transposes to bf16, wide (96 blocks) ----------
__global__ void prep_kernel(const float* __restrict__ Wkv, const float* __restrict__ Wp,
                            unsigned short* __restrict__ wkvT, unsigned short* __restrict__ wpT) {
  const int t = threadIdx.x;
  const int d = (t & 63) * 2;
  if (blockIdx.x < 64) {
    const int col = blockIdx.x * 4 + (t >> 6);
    unsigned short lo = f2bf(Wkv[d * 256 + col]);
    unsigned short hi = f2bf(Wkv[(d + 1) * 256 + col]);
    *reinterpret_cast<unsigned*>(&wkvT[col * 128 + d]) = (unsigned)lo | ((unsigned)hi << 16);
  } else {
    const int col = (blockIdx.x - 64) * 4 + (t >> 6);
    unsigned short lo = f2bf(Wp[d * 128 + col]);
    unsigned short hi = f2bf(Wp[(d + 1) * 128 + col]);
    *reinterpret_cast<unsigned*>(&wpT[col * 128 + d]) = (unsigned)lo | ((unsigned)hi << 16);
  }
}

// ---------- kv = x @ Wkv + bkv -> k_bf, vT_bf; blocks >= 256 do q scale+cast ----------
// GEMM part: 256 row-blocks (128 rows, all 256 output cols). Block 256 thr / 4 waves.
__global__ __launch_bounds__(256, 2) void kv_kernel(
    const float* __restrict__ x, const unsigned short* __restrict__ wkvT,
    const float* __restrict__ bkv, const float* __restrict__ q,
    unsigned short* __restrict__ kout, unsigned short* __restrict__ vtout,
    unsigned short* __restrict__ qo) {
  const int tid = threadIdx.x;
  if (blockIdx.x >= 256) {                  // q scale+cast tail blocks
    int i = ((blockIdx.x - 256) * 256 + tid) * 8;
    const float4* p = reinterpret_cast<const float4*>(q + i);
    float4 a = p[0], b = p[1];
    US8 o;
    o.us[0]=f2bf(a.x*EXPC); o.us[1]=f2bf(a.y*EXPC); o.us[2]=f2bf(a.z*EXPC); o.us[3]=f2bf(a.w*EXPC);
    o.us[4]=f2bf(b.x*EXPC); o.us[5]=f2bf(b.y*EXPC); o.us[6]=f2bf(b.z*EXPC); o.us[7]=f2bf(b.w*EXPC);
    *reinterpret_cast<US8*>(qo + i) = o;
    return;
  }
  __shared__ __align__(16) unsigned short WT[256 * 136];   // [col][d] stride 136 (69.6 KB)
  const int wv = tid >> 6, lane = tid & 63, l16 = lane & 15, quad = lane >> 4;
  const int row0 = blockIdx.x * 128;

  for (int p = 0; p < 16; ++p) {            // 4096 US8 chunks, b128 both sides
    int c = p * 256 + tid;
    int col = c >> 4, c16 = c & 15;
    *reinterpret_cast<US8*>(&WT[col * 136 + c16 * 8]) =
        *reinterpret_cast<const US8*>(wkvT + col * 128 + c16 * 8);
  }
  __syncthreads();

  bf16x8 afrag[2][4];
  for (int rg = 0; rg < 2; ++rg) {
    const int arow = row0 + wv * 32 + rg * 16 + l16;
    for (int s = 0; s < 4; ++s) {
      const float4* xp = reinterpret_cast<const float4*>(x + (size_t)arow * DIM + s * 32 + quad * 8);
      float4 u0 = xp[0], u1 = xp[1];
      US8 af;
      af.us[0]=f2bf(u0.x); af.us[1]=f2bf(u0.y); af.us[2]=f2bf(u0.z); af.us[3]=f2bf(u0.w);
      af.us[4]=f2bf(u1.x); af.us[5]=f2bf(u1.y); af.us[6]=f2bf(u1.z); af.us[7]=f2bf(u1.w);
      afrag[rg][s] = __builtin_bit_cast(bf16x8, af);
    }
  }
  f32x4 acc[2][16];
  for (int rg = 0; rg < 2; ++rg)
    for (int g = 0; g < 16; ++g) acc[rg][g] = f32x4{0.f, 0.f, 0.f, 0.f};
  for (int s = 0; s < 4; ++s)
    for (int g = 0; g < 16; ++g) {
      bf16x8 bfr = *reinterpret_cast<const bf16x8*>(&WT[(g * 16 + l16) * 136 + s * 32 + quad * 8]);
      acc[0][g] = __builtin_amdgcn_mfma_f32_16x16x32_bf16(afrag[0][s], bfr, acc[0][g], 0, 0, 0);
      acc[1][g] = __builtin_amdgcn_mfma_f32_16x16x32_bf16(afrag[1][s], bfr, acc[1][g], 0, 0, 0);
    }

  // k half: direct stores
  for (int rg = 0; rg < 2; ++rg)
    for (int g = 0; g < 8; ++g) {
      float bias = bkv[g * 16 + l16];
      for (int r = 0; r < 4; ++r) {
        int orow = row0 + wv * 32 + rg * 16 + quad * 4 + r;   // C/D: row=quad*4+r, col=l16
        kout[(size_t)orow * DIM + g * 16 + l16] = f2bf(acc[rg][g][r] + bias);
      }
    }
  // v half: transpose through LDS (reuse WT), then b128 copies out
  __syncthreads();
  unsigned short* LDSt = WT;                // [d][n_local] stride 136
  for (int rg = 0; rg < 2; ++rg)
    for (int g = 0; g < 8; ++g) {
      float bias = bkv[128 + g * 16 + l16];
      for (int r = 0; r < 4; ++r)
        LDSt[(g * 16 + l16) * 136 + wv * 32 + rg * 16 + quad * 4 + r] = f2bf(acc[rg][g + 8][r] + bias);
    }
  __syncthreads();
  const int bb = row0 >> 12, n0 = row0 & (NSEQ - 1);
  unsigned short* vb = vtout + (size_t)bb * NSEQ * DIM;
  for (int p = 0; p < 8; ++p) {             // 2048 chunks: 128 d x 16
    int c = p * 256 + tid;
    int d = c >> 4, c8 = c & 15;
    *reinterpret_cast<US8*>(vb + (size_t)d * NSEQ + n0 + c8 * 8) =
        *reinterpret_cast<const US8*>(&LDSt[d * 136 + c8 * 8]);
  }
}

// ---------- flash attention partials: Q:=k, K:=q_hat, V:=v -> fp32 O/l partials ----------
// grid 512 = 8 batches (blockIdx&7 -> XCD pin) x 32 q-tiles (128 rows) x 2 key-splits.
// Block 256 thr = 4 q-waves x 32 rows sharing one 64-key K/V^T tile. LDS 54.3 KB -> 2 blocks/CU.
// S computed TRANSPOSED (mfma operands swapped): lane holds S^T[m=g*16+quad*4+r][n=l16],
// so P's 4 r-values are m-consecutive in-lane -> packed dword pairs -> ds_write_b64.
// This kills the 16-bit LDS scatter writes that R1..R7 data shows are the conflict source
// (conflicts track u16-write count: 48/thr->136 cyc, 32/thr->~150 cyc; swizzles no effect).
__global__ __launch_bounds__(256, 2) void attn_kernel(
    const unsigned short* __restrict__ kbuf, const unsigned short* __restrict__ qbuf,
    const unsigned short* __restrict__ vtbuf,
    float* __restrict__ opart, float* __restrict__ lpart) {
  // shorts: Ksh 64x136 = 8704 | VTsh 128x72 = 9216 | Psh 4x32x72 = 9216
  __shared__ __align__(16) unsigned short SH[27136];   // 54272 B
  const int tid = threadIdx.x;
  const int wv = tid >> 6, lane = tid & 63, l16 = lane & 15, quad = lane >> 4;
  const int b = blockIdx.x & 7;
  const int t = blockIdx.x >> 3;
  const int q0 = (t & 31) * 128;
  const int kh = t >> 5;
  const int key0 = kh * (NSEQ / KH);
  const unsigned short* kb = kbuf + (size_t)b * NSEQ * DIM;
  const unsigned short* qb = qbuf + (size_t)b * NSEQ * DIM;
  const unsigned short* vtb = vtbuf + (size_t)b * NSEQ * DIM;

  unsigned short* Ksh  = SH;                      // [m][d] stride 136
  unsigned short* VTsh = SH + 8704;               // [d][m] stride 72
  unsigned short* pp   = SH + 17920 + wv * 2304;  // per-wave P [n][m] stride 72

  // frags of this wave's 32 "query" rows of k (used as the mfma B operand)
  bf16x8 afrag[2][4];
  for (int rg = 0; rg < 2; ++rg) {
    const int arow = q0 + wv * 32 + rg * 16 + l16;
    for (int s = 0; s < 4; ++s)
      afrag[rg][s] = __builtin_bit_cast(bf16x8,
          *reinterpret_cast<const US8*>(kb + (size_t)arow * DIM + s * 32 + quad * 8));
  }

  f32x4 Oacc[2][8];
  for (int rg = 0; rg < 2; ++rg)
    for (int g = 0; g < 8; ++g) Oacc[rg][g] = f32x4{0.f, 0.f, 0.f, 0.f};
  float lsum[2] = {0.f, 0.f};

  for (int it = 0; it < NSEQ / KH / 64; ++it) {
    const int m0 = key0 + it * 64;
    __syncthreads();                       // prior iter's reads done before overwrite
    for (int p = 0; p < 4; ++p) {          // stage K tile: 1024 b128 chunks
      int c = p * 256 + tid;
      int row = c >> 4, c16 = c & 15;
      *reinterpret_cast<US8*>(&Ksh[row * 136 + c16 * 8]) =
          *reinterpret_cast<const US8*>(qb + (size_t)(m0 + row) * DIM + c16 * 8);
    }
    for (int p = 0; p < 4; ++p) {          // stage V^T tile: b128 chunks
      int c = p * 256 + tid;
      int d = c >> 3, c8 = c & 7;
      *reinterpret_cast<US8*>(&VTsh[d * 72 + c8 * 8]) =
          *reinterpret_cast<const US8*>(vtb + (size_t)d * NSEQ + m0 + c8 * 8);
    }
    __syncthreads();

    // S^T[64 m][16 n] per rg: operands swapped (A = K-hat rows, B = k rows)
    f32x4 S[2][4];
    for (int rg = 0; rg < 2; ++rg)
      for (int g = 0; g < 4; ++g) S[rg][g] = f32x4{0.f, 0.f, 0.f, 0.f};
    for (int s = 0; s < 4; ++s)
      for (int g = 0; g < 4; ++g) {
        bf16x8 afr = *reinterpret_cast<const bf16x8*>(&Ksh[(g * 16 + l16) * 136 + s * 32 + quad * 8]);
        S[0][g] = __builtin_amdgcn_mfma_f32_16x16x32_bf16(afr, afrag[0][s], S[0][g], 0, 0, 0);
        S[1][g] = __builtin_amdgcn_mfma_f32_16x16x32_bf16(afr, afrag[1][s], S[1][g], 0, 0, 0);
      }

    // P = exp2(S^T) (q pre-scaled), bf16-truncated, packed in-lane (r = consecutive m),
    // stored to P[n = rg*16+l16][m = g*16+quad*4 .. +3] with one ds_write_b64 per (rg,g).
    for (int rg = 0; rg < 2; ++rg) {
      float ls = 0.f;
      for (int g = 0; g < 4; ++g) {
        unsigned u0 = __builtin_bit_cast(unsigned, exp2f(S[rg][g][0])) & 0xffff0000u;
        unsigned u1 = __builtin_bit_cast(unsigned, exp2f(S[rg][g][1])) & 0xffff0000u;
        unsigned u2 = __builtin_bit_cast(unsigned, exp2f(S[rg][g][2])) & 0xffff0000u;
        unsigned u3 = __builtin_bit_cast(unsigned, exp2f(S[rg][g][3])) & 0xffff0000u;
        ls += __builtin_bit_cast(float, u0) + __builtin_bit_cast(float, u1)
            + __builtin_bit_cast(float, u2) + __builtin_bit_cast(float, u3);
        uint2 pk;
        pk.x = (u0 >> 16) | u1;
        pk.y = (u2 >> 16) | u3;
        *reinterpret_cast<uint2*>(&pp[(rg * 16 + l16) * 72 + g * 16 + quad * 4]) = pk;
      }
      lsum[rg] += ls;
    }

    asm volatile("s_waitcnt lgkmcnt(0)" ::: "memory");  // wave-private P write->read

    // O += P @ V : pa reads P row-major [n][m] (b128, bank-uniform)
    for (int s2 = 0; s2 < 2; ++s2) {
      bf16x8 pa0 = *reinterpret_cast<const bf16x8*>(&pp[l16 * 72 + s2 * 32 + quad * 8]);
      bf16x8 pa1 = *reinterpret_cast<const bf16x8*>(&pp[(16 + l16) * 72 + s2 * 32 + quad * 8]);
      for (int g = 0; g < 8; ++g) {
        bf16x8 vfr = *reinterpret_cast<const bf16x8*>(&VTsh[(g * 16 + l16) * 72 + s2 * 32 + quad * 8]);
        Oacc[0][g] = __builtin_amdgcn_mfma_f32_16x16x32_bf16(pa0, vfr, Oacc[0][g], 0, 0, 0);
        Oacc[1][g] = __builtin_amdgcn_mfma_f32_16x16x32_bf16(pa1, vfr, Oacc[1][g], 0, 0, 0);
      }
    }
  }

  // lsum: per-lane partial over its 16 m-values; total via quad butterfly (n = l16 fixed)
  for (int rg = 0; rg < 2; ++rg) {
    float v = lsum[rg];
    v += __shfl_xor(v, 16);
    v += __shfl_xor(v, 32);
    lsum[rg] = v;
  }
  if (quad == 0) {
    float* lp = lpart + (size_t)kh * ROWS + (size_t)b * NSEQ + q0 + wv * 32;
    lp[l16] = lsum[0];
    lp[16 + l16] = lsum[1];
  }
  float* ob = opart + (size_t)kh * ROWS * DIM + ((size_t)b * NSEQ + q0 + wv * 32) * DIM;
  for (int rg = 0; rg < 2; ++rg)
    for (int g = 0; g < 8; ++g)
      for (int r = 0; r < 4; ++r)
        ob[(rg * 16 + quad * 4 + r) * DIM + g * 16 + l16] = Oacc[rg][g][r];
}

// ---------- combine fp32 partials, normalize, out = o @ Wp + bp (fp32 out) ----------
// grid 256, block 256 / 4 waves; wave: 32 rows.
__global__ __launch_bounds__(256, 2) void combine_proj_kernel(
    const float* __restrict__ opart, const float* __restrict__ lpart,
    const unsigned short* __restrict__ wpT, const float* __restrict__ bp,
    float* __restrict__ out) {
  __shared__ __align__(16) unsigned short WT[128 * 136];
  const int tid = threadIdx.x;
  const int wv = tid >> 6, lane = tid & 63, l16 = lane & 15, quad = lane >> 4;
  const int row0 = blockIdx.x * 128;

  for (int p = 0; p < 8; ++p) {
    int c = p * 256 + tid;
    int col = c >> 4, c16 = c & 15;
    *reinterpret_cast<US8*>(&WT[col * 136 + c16 * 8]) =
        *reinterpret_cast<const US8*>(wpT + col * 128 + c16 * 8);
  }
  __syncthreads();

  f32x4 acc[2][8];
  for (int rg = 0; rg < 2; ++rg)
    for (int g = 0; g < 8; ++g) acc[rg][g] = f32x4{0.f, 0.f, 0.f, 0.f};
  for (int rg = 0; rg < 2; ++rg) {
    const int arow = row0 + wv * 32 + rg * 16 + l16;
    float linv = 1.f / (lpart[arow] + lpart[ROWS + arow]);
    for (int s = 0; s < 4; ++s) {
      const size_t base = (size_t)arow * DIM + s * 32 + quad * 8;
      float4 s0 = *reinterpret_cast<const float4*>(opart + base);
      float4 s1 = *reinterpret_cast<const float4*>(opart + base + 4);
      float4 u0 = *reinterpret_cast<const float4*>(opart + (size_t)ROWS * DIM + base);
      float4 u1 = *reinterpret_cast<const float4*>(opart + (size_t)ROWS * DIM + base + 4);
      US8 af;
      af.us[0]=f2bf((s0.x+u0.x)*linv); af.us[1]=f2bf((s0.y+u0.y)*linv);
      af.us[2]=f2bf((s0.z+u0.z)*linv); af.us[3]=f2bf((s0.w+u0.w)*linv);
      af.us[4]=f2bf((s1.x+u1.x)*linv); af.us[5]=f2bf((s1.y+u1.y)*linv);
      af.us[6]=f2bf((s1.z+u1.z)*linv); af.us[7]=f2bf((s1.w+u1.w)*linv);
      bf16x8 a = __builtin_bit_cast(bf16x8, af);
      for (int g = 0; g < 8; ++g) {
        bf16x8 bfr = *reinterpret_cast<const bf16x8*>(&WT[(g * 16 + l16) * 136 + s * 32 + quad * 8]);
        acc[rg][g] = __builtin_amdgcn_mfma_f32_16x16x32_bf16(a, bfr, acc[rg][g], 0, 0, 0);
      }
    }
  }
  for (int rg = 0; rg < 2; ++rg)
    for (int g = 0; g < 8; ++g) {
      float bias = bp[g * 16 + l16];
      for (int r = 0; r < 4; ++r) {
        int orow = row0 + wv * 32 + rg * 16 + quad * 4 + r;
        out[(size_t)orow * DIM + g * 16 + l16] = acc[rg][g][r] + bias;
      }
    }
}

extern "C" void kernel_launch(void* const* d_in, const int* in_sizes, int n_in,
                              void* d_out, int out_size, void* d_ws, size_t ws_size,
                              hipStream_t stream) {
  (void)in_sizes; (void)n_in; (void)out_size; (void)ws_size;
  const float* x   = (const float*)d_in[0];
  const float* qg  = (const float*)d_in[1];
  const float* Wkv = (const float*)d_in[2];
  const float* bkv = (const float*)d_in[3];
  const float* Wp  = (const float*)d_in[4];
  const float* bp  = (const float*)d_in[5];
  float* out = (float*)d_out;

  // workspace: 3x bf16 bufs 25.2MB | weights 96KB | l 256KB | O partials (fp32, KH=2) 33.6MB
  unsigned short* qbf  = (unsigned short*)d_ws;
  unsigned short* kbf  = qbf + (size_t)ROWS * DIM;
  unsigned short* vtbf = kbf + (size_t)ROWS * DIM;
  unsigned short* wkvT = vtbf + (size_t)ROWS * DIM;
  unsigned short* wpT  = wkvT + 256 * 128;
  float* lpart = (float*)(wpT + 128 * 128);
  float* opart = lpart + (size_t)KH * ROWS;

  hipLaunchKernelGGL(prep_kernel, dim3(96), dim3(256), 0, stream, Wkv, Wp, wkvT, wpT);
  hipLaunchKernelGGL(kv_kernel, dim3(256 + 2048), dim3(256), 0, stream,
                     x, wkvT, bkv, qg, kbf, vtbf, qbf);
  hipLaunchKernelGGL(attn_kernel, dim3(8 * 32 * KH), dim3(256), 0, stream, kbf, qbf, vtbf, opart, lpart);
  hipLaunchKernelGGL(combine_proj_kernel, dim3(ROWS / 128), dim3(256), 0, stream, opart, lpart, wpT, bp, out);
}

// Round 9
// 190.239 us; speedup vs baseline: 1.0347x; 1.0347x over previous
//
#include <hip/hip_runtime.h>

// ---------- types / helpers ----------
typedef __bf16 bf16x8 __attribute__((ext_vector_type(8)));
typedef float f32x4 __attribute__((ext_vector_type(4)));
typedef float f32x16 __attribute__((ext_vector_type(16)));

struct alignas(16) US8 { unsigned short us[8]; };

static __device__ inline unsigned short f2bf(float f) {
  union { float f; unsigned u; } v; v.f = f;
  unsigned r = v.u + 0x7fffu + ((v.u >> 16) & 1u);   // RNE
  return (unsigned short)(r >> 16);
}

static __device__ inline void gload16(const unsigned short* g, unsigned short* l) {
  // direct-to-LDS DMA, 16B/lane; LDS dest = wave-uniform base + lane*16
  __builtin_amdgcn_global_load_lds(
      (const __attribute__((address_space(1))) void*)g,
      (__attribute__((address_space(3))) void*)l, 16, 0, 0);
}

// B=8, N=4096, D=128.  32768 total rows.
#define NSEQ 4096
#define DIM 128
#define ROWS 32768
#define KH 2                      // cross-block key splits in attn

// log2(e)/sqrt(128): folded into q so S exits QK^T already in log2 domain
#define EXPC (1.4426950408889634f * 0.08838834764831845f)

// ---------- prep: weight transposes to bf16, wide (96 blocks) ----------
__global__ void prep_kernel(const float* __restrict__ Wkv, const float* __restrict__ Wp,
                            unsigned short* __restrict__ wkvT, unsigned short* __restrict__ wpT) {
  const int t = threadIdx.x;
  const int d = (t & 63) * 2;
  if (blockIdx.x < 64) {
    const int col = blockIdx.x * 4 + (t >> 6);
    unsigned short lo = f2bf(Wkv[d * 256 + col]);
    unsigned short hi = f2bf(Wkv[(d + 1) * 256 + col]);
    *reinterpret_cast<unsigned*>(&wkvT[col * 128 + d]) = (unsigned)lo | ((unsigned)hi << 16);
  } else {
    const int col = (blockIdx.x - 64) * 4 + (t >> 6);
    unsigned short lo = f2bf(Wp[d * 128 + col]);
    unsigned short hi = f2bf(Wp[(d + 1) * 128 + col]);
    *reinterpret_cast<unsigned*>(&wpT[col * 128 + d]) = (unsigned)lo | ((unsigned)hi << 16);
  }
}

// ---------- kv = x @ Wkv + bkv -> k_bf (row-major), v BLOCKED+PERMUTED; q blocked cast ----------
// Blocked V layout per batch: [tile(64 keys)][chunk 16][lane 64][8] where chunk=(mg,dh):
//   element (chunk, l, j) = V[m' = mg*8+j][d = dh*64+l], m' = key order with bit2<->bit3
//   swapped per 16-block (matches 32x32 MFMA C/D->A reg order in attn's PV).
// Blocked q_hat layout per batch: [tile(64 rows)][kc 16][lane 64][8]:
//   element = q_hat[row = tile*64+l][d = kc*8+j].
__global__ __launch_bounds__(256, 2) void kv_kernel(
    const float* __restrict__ x, const unsigned short* __restrict__ wkvT,
    const float* __restrict__ bkv, const float* __restrict__ q,
    unsigned short* __restrict__ kout, unsigned short* __restrict__ vtout,
    unsigned short* __restrict__ qo) {
  const int tid = threadIdx.x;
  if (blockIdx.x >= 256) {                  // q scale+cast tail blocks -> blocked layout
    int i = ((blockIdx.x - 256) * 256 + tid) * 8;
    const float4* p = reinterpret_cast<const float4*>(q + i);
    float4 a = p[0], b = p[1];
    US8 o;
    o.us[0]=f2bf(a.x*EXPC); o.us[1]=f2bf(a.y*EXPC); o.us[2]=f2bf(a.z*EXPC); o.us[3]=f2bf(a.w*EXPC);
    o.us[4]=f2bf(b.x*EXPC); o.us[5]=f2bf(b.y*EXPC); o.us[6]=f2bf(b.z*EXPC); o.us[7]=f2bf(b.w*EXPC);
    int row = i >> 7, d0 = i & 127;
    int bb = row >> 12, n = row & (NSEQ - 1), tile = n >> 6, l = n & 63, kc = d0 >> 3;
    *reinterpret_cast<US8*>(qo + (size_t)bb * NSEQ * DIM + tile * 8192 + kc * 512 + l * 8) = o;
    return;
  }
  __shared__ __align__(16) unsigned short WT[256 * 136];   // [col][d] stride 136 (69.6 KB)
  const int wv = tid >> 6, lane = tid & 63, l16 = lane & 15, quad = lane >> 4;
  const int row0 = blockIdx.x * 128;

  for (int p = 0; p < 16; ++p) {            // 4096 US8 chunks, b128 both sides
    int c = p * 256 + tid;
    int col = c >> 4, c16 = c & 15;
    *reinterpret_cast<US8*>(&WT[col * 136 + c16 * 8]) =
        *reinterpret_cast<const US8*>(wkvT + col * 128 + c16 * 8);
  }
  __syncthreads();

  bf16x8 afrag[2][4];
  for (int rg = 0; rg < 2; ++rg) {
    const int arow = row0 + wv * 32 + rg * 16 + l16;
    for (int s = 0; s < 4; ++s) {
      const float4* xp = reinterpret_cast<const float4*>(x + (size_t)arow * DIM + s * 32 + quad * 8);
      float4 u0 = xp[0], u1 = xp[1];
      US8 af;
      af.us[0]=f2bf(u0.x); af.us[1]=f2bf(u0.y); af.us[2]=f2bf(u0.z); af.us[3]=f2bf(u0.w);
      af.us[4]=f2bf(u1.x); af.us[5]=f2bf(u1.y); af.us[6]=f2bf(u1.z); af.us[7]=f2bf(u1.w);
      afrag[rg][s] = __builtin_bit_cast(bf16x8, af);
    }
  }
  f32x4 acc[2][16];
  for (int rg = 0; rg < 2; ++rg)
    for (int g = 0; g < 16; ++g) acc[rg][g] = f32x4{0.f, 0.f, 0.f, 0.f};
  for (int s = 0; s < 4; ++s)
    for (int g = 0; g < 16; ++g) {
      bf16x8 bfr = *reinterpret_cast<const bf16x8*>(&WT[(g * 16 + l16) * 136 + s * 32 + quad * 8]);
      acc[0][g] = __builtin_amdgcn_mfma_f32_16x16x32_bf16(afrag[0][s], bfr, acc[0][g], 0, 0, 0);
      acc[1][g] = __builtin_amdgcn_mfma_f32_16x16x32_bf16(afrag[1][s], bfr, acc[1][g], 0, 0, 0);
    }

  // k half: direct stores (row-major)
  for (int rg = 0; rg < 2; ++rg)
    for (int g = 0; g < 8; ++g) {
      float bias = bkv[g * 16 + l16];
      for (int r = 0; r < 4; ++r) {
        int orow = row0 + wv * 32 + rg * 16 + quad * 4 + r;   // C/D: row=quad*4+r, col=l16
        kout[(size_t)orow * DIM + g * 16 + l16] = f2bf(acc[rg][g][r] + bias);
      }
    }
  // v half: transpose through LDS (stride 140), then blocked+permuted b128 global stores
  __syncthreads();
  unsigned short* LDSt = WT;                // [d][n_local] stride 140
  for (int rg = 0; rg < 2; ++rg)
    for (int g = 0; g < 8; ++g) {
      float bias = bkv[128 + g * 16 + l16];
      for (int r = 0; r < 4; ++r)
        LDSt[(g * 16 + l16) * 140 + wv * 32 + rg * 16 + quad * 4 + r] = f2bf(acc[rg][g + 8][r] + bias);
    }
  __syncthreads();
  const int bb = row0 >> 12, tilebase = (row0 & (NSEQ - 1)) >> 6;
  unsigned short* vbo = vtout + (size_t)bb * NSEQ * DIM;
  for (int p = 0; p < 8; ++p) {             // 2048 16B units: 2 tiles x 16 chunks x 64 lanes
    int c = p * 256 + tid;
    int tl = c >> 10, u = c & 1023, idx = u >> 6, l = u & 63;
    int mg = idx >> 1, dh = idx & 1, d = dh * 64 + l;
    int nb = tl * 64 + (mg >> 1) * 16 + (mg & 1) * 4;   // first 4-run (bit2<->3 swap)
    uint2 lo = *reinterpret_cast<const uint2*>(&LDSt[d * 140 + nb]);
    uint2 hi = *reinterpret_cast<const uint2*>(&LDSt[d * 140 + nb + 8]);
    uint4 o{lo.x, lo.y, hi.x, hi.y};
    *reinterpret_cast<uint4*>(vbo + (size_t)(tilebase + tl) * 8192 + idx * 512 + l * 8) = o;
  }
}

// ---------- flash attention partials (32x32x16 MFMA, register-P, DMA staging) ----------
// grid 512 = 8 batches (blockIdx&7) x 32 q-tiles (128 rows) x 2 key-splits.
// Block 256 thr = 4 q-waves x 32 rows; one 64-key K-hat/V tile in LDS (32 KB -> 2+ blocks/CU).
// S computed transposed via mfma_f32_32x32x16_bf16 (A = q_hat keys, B = k rows): D col=lane&31
// = q-row == PV A-operand row => P stays in registers (exp2+truncate+pack in-lane; the V
// global key-permutation makes A/B contraction orders agree). Staging via global_load_lds.
__global__ __launch_bounds__(256, 2) void attn_kernel(
    const unsigned short* __restrict__ kbuf, const unsigned short* __restrict__ qblk,
    const unsigned short* __restrict__ vblk,
    float* __restrict__ opart, float* __restrict__ lpart) {
  __shared__ __align__(16) unsigned short SH[16384];   // Ksh 8192 | Vsh 8192 (32 KB)
  unsigned short* Ksh = SH;
  unsigned short* Vsh = SH + 8192;
  const int tid = threadIdx.x;
  const int wv = tid >> 6, lane = tid & 63, l32 = lane & 31, h = lane >> 5;
  const int b = blockIdx.x & 7;
  const int t = blockIdx.x >> 3;
  const int q0 = (t & 31) * 128;
  const int kh = t >> 5;
  const int key0 = kh * (NSEQ / KH);
  const unsigned short* kb = kbuf + (size_t)b * NSEQ * DIM;
  const unsigned short* qb = qblk + (size_t)b * NSEQ * DIM;
  const unsigned short* vb = vblk + (size_t)b * NSEQ * DIM;

  // B-operand frags: this wave's 32 q-rows of k. B[k=h*8+j][n=l32]
  bf16x8 kfrag[8];
  for (int ks = 0; ks < 8; ++ks)
    kfrag[ks] = __builtin_bit_cast(bf16x8, *reinterpret_cast<const US8*>(
        kb + (size_t)(q0 + wv * 32 + l32) * DIM + ks * 16 + h * 8));

  f32x16 Oacc[4];
  for (int dt = 0; dt < 4; ++dt)
    for (int i = 0; i < 16; ++i) Oacc[dt][i] = 0.f;
  float lsum = 0.f;

  for (int it = 0; it < NSEQ / KH / 64; ++it) {
    const int tile = (key0 + it * 64) >> 6;
    __syncthreads();                        // prior iter's reads done before overwrite
    for (int c = 0; c < 8; ++c) {           // DMA stage: 32 chunks / 4 waves
      int idx = wv * 8 + c;
      if (idx < 16)
        gload16(qb + (size_t)tile * 8192 + idx * 512 + lane * 8, &Ksh[idx * 512]);
      else
        gload16(vb + (size_t)tile * 8192 + (idx - 16) * 512 + lane * 8, &Vsh[(idx - 16) * 512]);
    }
    __syncthreads();                        // drains vmcnt -> staged data visible

    // S^T tiles: D[m 32][n 32] = sum_ks A(K-hat)[m][k] * B(k-rows)[k][n]
    f32x16 S0, S1;
    for (int i = 0; i < 16; ++i) { S0[i] = 0.f; S1[i] = 0.f; }
    for (int ks = 0; ks < 8; ++ks) {
      const unsigned short* kc = &Ksh[(ks * 2 + h) * 512];
      bf16x8 a0 = *reinterpret_cast<const bf16x8*>(&kc[l32 * 8]);
      bf16x8 a1 = *reinterpret_cast<const bf16x8*>(&kc[(32 + l32) * 8]);
      S0 = __builtin_amdgcn_mfma_f32_32x32x16_bf16(a0, kfrag[ks], S0, 0, 0, 0);
      S1 = __builtin_amdgcn_mfma_f32_32x32x16_bf16(a1, kfrag[ks], S1, 0, 0, 0);
    }

    // P = exp2(S^T) truncated to bf16, packed in-lane: frag (T,s) = regs s*8..s*8+7
    bf16x8 pf[2][2];
    for (int T = 0; T < 2; ++T) {
      unsigned pk[8];
      for (int i2 = 0; i2 < 8; ++i2) {
        float e0 = exp2f(T ? S1[i2 * 2] : S0[i2 * 2]);
        float e1 = exp2f(T ? S1[i2 * 2 + 1] : S0[i2 * 2 + 1]);
        unsigned u0 = __builtin_bit_cast(unsigned, e0) & 0xffff0000u;
        unsigned u1 = __builtin_bit_cast(unsigned, e1) & 0xffff0000u;
        lsum += __builtin_bit_cast(float, u0) + __builtin_bit_cast(float, u1);
        pk[i2] = (u0 >> 16) | u1;
      }
      pf[T][0] = __builtin_bit_cast(bf16x8, uint4{pk[0], pk[1], pk[2], pk[3]});
      pf[T][1] = __builtin_bit_cast(bf16x8, uint4{pk[4], pk[5], pk[6], pk[7]});
    }

    // O[n][d] += P[n][m] * V[m][d]: A = pf (regs), B = Vsh chunks (mg = 4T+2s+h)
    for (int T = 0; T < 2; ++T)
      for (int s = 0; s < 2; ++s) {
        const int mg = 4 * T + 2 * s + h;
        for (int dt = 0; dt < 4; ++dt) {
          bf16x8 bv = *reinterpret_cast<const bf16x8*>(
              &Vsh[(mg * 2 + (dt >> 1)) * 512 + ((dt & 1) * 32 + l32) * 8]);
          Oacc[dt] = __builtin_amdgcn_mfma_f32_32x32x16_bf16(pf[T][s], bv, Oacc[dt], 0, 0, 0);
        }
      }
  }

  // l: per-lane covers its h-half of m for q-row n=l32; merge halves
  {
    float v = lsum;
    v += __shfl_xor(v, 32);
    if (lane < 32)
      lpart[(size_t)kh * ROWS + (size_t)b * NSEQ + q0 + wv * 32 + l32] = v;
  }
  float* ob = opart + (size_t)kh * ROWS * DIM + ((size_t)b * NSEQ + q0 + wv * 32) * DIM;
  for (int dt = 0; dt < 4; ++dt)
    for (int i = 0; i < 16; ++i) {
      int n = (i & 3) + 8 * (i >> 2) + 4 * h;   // 32x32 C/D row map (measured m74/m101)
      ob[n * DIM + dt * 32 + l32] = Oacc[dt][i];
    }
}

// ---------- combine fp32 partials, normalize, out = o @ Wp + bp (fp32 out) ----------
__global__ __launch_bounds__(256, 2) void combine_proj_kernel(
    const float* __restrict__ opart, const float* __restrict__ lpart,
    const unsigned short* __restrict__ wpT, const float* __restrict__ bp,
    float* __restrict__ out) {
  __shared__ __align__(16) unsigned short WT[128 * 136];
  const int tid = threadIdx.x;
  const int wv = tid >> 6, lane = tid & 63, l16 = lane & 15, quad = lane >> 4;
  const int row0 = blockIdx.x * 128;

  for (int p = 0; p < 8; ++p) {
    int c = p * 256 + tid;
    int col = c >> 4, c16 = c & 15;
    *reinterpret_cast<US8*>(&WT[col * 136 + c16 * 8]) =
        *reinterpret_cast<const US8*>(wpT + col * 128 + c16 * 8);
  }
  __syncthreads();

  f32x4 acc[2][8];
  for (int rg = 0; rg < 2; ++rg)
    for (int g = 0; g < 8; ++g) acc[rg][g] = f32x4{0.f, 0.f, 0.f, 0.f};
  for (int rg = 0; rg < 2; ++rg) {
    const int arow = row0 + wv * 32 + rg * 16 + l16;
    float linv = 1.f / (lpart[arow] + lpart[ROWS + arow]);
    for (int s = 0; s < 4; ++s) {
      const size_t base = (size_t)arow * DIM + s * 32 + quad * 8;
      float4 s0 = *reinterpret_cast<const float4*>(opart + base);
      float4 s1 = *reinterpret_cast<const float4*>(opart + base + 4);
      float4 u0 = *reinterpret_cast<const float4*>(opart + (size_t)ROWS * DIM + base);
      float4 u1 = *reinterpret_cast<const float4*>(opart + (size_t)ROWS * DIM + base + 4);
      US8 af;
      af.us[0]=f2bf((s0.x+u0.x)*linv); af.us[1]=f2bf((s0.y+u0.y)*linv);
      af.us[2]=f2bf((s0.z+u0.z)*linv); af.us[3]=f2bf((s0.w+u0.w)*linv);
      af.us[4]=f2bf((s1.x+u1.x)*linv); af.us[5]=f2bf((s1.y+u1.y)*linv);
      af.us[6]=f2bf((s1.z+u1.z)*linv); af.us[7]=f2bf((s1.w+u1.w)*linv);
      bf16x8 a = __builtin_bit_cast(bf16x8, af);
      for (int g = 0; g < 8; ++g) {
        bf16x8 bfr = *reinterpret_cast<const bf16x8*>(&WT[(g * 16 + l16) * 136 + s * 32 + quad * 8]);
        acc[rg][g] = __builtin_amdgcn_mfma_f32_16x16x32_bf16(a, bfr, acc[rg][g], 0, 0, 0);
      }
    }
  }
  for (int rg = 0; rg < 2; ++rg)
    for (int g = 0; g < 8; ++g) {
      float bias = bp[g * 16 + l16];
      for (int r = 0; r < 4; ++r) {
        int orow = row0 + wv * 32 + rg * 16 + quad * 4 + r;
        out[(size_t)orow * DIM + g * 16 + l16] = acc[rg][g][r] + bias;
      }
    }
}

extern "C" void kernel_launch(void* const* d_in, const int* in_sizes, int n_in,
                              void* d_out, int out_size, void* d_ws, size_t ws_size,
                              hipStream_t stream) {
  (void)in_sizes; (void)n_in; (void)out_size; (void)ws_size;
  const float* x   = (const float*)d_in[0];
  const float* qg  = (const float*)d_in[1];
  const float* Wkv = (const float*)d_in[2];
  const float* bkv = (const float*)d_in[3];
  const float* Wp  = (const float*)d_in[4];
  const float* bp  = (const float*)d_in[5];
  float* out = (float*)d_out;

  // workspace: 3x bf16 bufs 25.2MB | weights 96KB | l 256KB | O partials (fp32, KH=2) 33.6MB
  unsigned short* qbf  = (unsigned short*)d_ws;
  unsigned short* kbf  = qbf + (size_t)ROWS * DIM;
  unsigned short* vtbf = kbf + (size_t)ROWS * DIM;
  unsigned short* wkvT = vtbf + (size_t)ROWS * DIM;
  unsigned short* wpT  = wkvT + 256 * 128;
  float* lpart = (float*)(wpT + 128 * 128);
  float* opart = lpart + (size_t)KH * ROWS;

  hipLaunchKernelGGL(prep_kernel, dim3(96), dim3(256), 0, stream, Wkv, Wp, wkvT, wpT);
  hipLaunchKernelGGL(kv_kernel, dim3(256 + 2048), dim3(256), 0, stream,
                     x, wkvT, bkv, qg, kbf, vtbf, qbf);
  hipLaunchKernelGGL(attn_kernel, dim3(8 * 32 * KH), dim3(256), 0, stream, kbf, qbf, vtbf, opart, lpart);
  hipLaunchKernelGGL(combine_proj_kernel, dim3(ROWS / 128), dim3(256), 0, stream, opart, lpart, wpT, bp, out);
}